// Round 19
// baseline (133.739 us; speedup 1.0000x reference)
//
#include <hip/hip_runtime.h>
#include <math.h>

#define NEG_SLOPE 0.01f
#define NB 256           // buckets (bucket = dst >> 9, 512 nodes each)
#define BATCH 4096       // edges per hist/P3 batch (16 per thread)
#define HROW 264         // bf16 row stride in LDS: 256 elems + 8 pad (528 B)

typedef __attribute__((ext_vector_type(8))) short short8;
typedef __attribute__((ext_vector_type(4))) float f32x4;

__device__ __forceinline__ unsigned short f2bf_rne(float f) {
    unsigned u = __float_as_uint(f);
    unsigned r = 0x7fffu + ((u >> 16) & 1u);
    return (unsigned short)((u + r) >> 16);
}
__device__ __forceinline__ float bf2f(unsigned short b) {
    return __uint_as_float(((unsigned)b) << 16);
}
// 2 f32 -> 2 bf16 (RNE), single instruction (verified on-device R9/R11/R13)
__device__ __forceinline__ unsigned cvtpk(float lo, float hi) {
    unsigned r;
    asm("v_cvt_pk_bf16_f32 %0, %1, %2" : "=v"(r) : "v"(lo), "v"(hi));
    return r;
}

// ---------------------------------------------------------------------------
// K1 = {bucket-histogram || w-prep (fc_w -> bf16 hi/lo)} -- both cheap
// ---------------------------------------------------------------------------
__global__ __launch_bounds__(256) void k_hist(
    const int* __restrict__ dst, int* __restrict__ hist_blk, int n_edges,
    const float* __restrict__ fc_w,
    unsigned short* __restrict__ w_hi, unsigned short* __restrict__ w_lo, int wdim)
{
    const int tid = threadIdx.x;
    const int nbatch = (n_edges + BATCH - 1) / BATCH;
    if ((int)blockIdx.x < nbatch) {
        __shared__ int hist[NB];
        const int batch = blockIdx.x;
        hist[tid] = 0;
        __syncthreads();
        const int e0 = batch * BATCH;
        const int n = min(BATCH, n_edges - e0);
        #pragma unroll
        for (int k = 0; k < 16; ++k) {
            int j = tid + k * 256;
            if (j < n) atomicAdd(&hist[dst[e0 + j] >> 9], 1);
        }
        __syncthreads();
        hist_blk[batch * NB + tid] = hist[tid];
    } else {
        int i = (blockIdx.x - nbatch) * 256 + tid;
        if (i < wdim) {
            float f = fc_w[i];
            unsigned u = __float_as_uint(f);
            w_hi[i] = (unsigned short)(u >> 16);
            float lo = f - __uint_as_float(u & 0xffff0000u);
            w_lo[i] = f2bf_rne(lo);
        }
    }
}

// ---------------------------------------------------------------------------
// P2loc (NB blocks): per-bucket exclusive scan over batches -> bb (local),
// bucket_tot. Parallel across 256 CUs.
// ---------------------------------------------------------------------------
__global__ __launch_bounds__(256) void k_p2loc(
    const int* __restrict__ hist_blk, int* __restrict__ bb,
    int* __restrict__ bucket_tot, int n_edges)
{
    const int tid = threadIdx.x;
    const int b = blockIdx.x;
    const int nbatch = (n_edges + BATCH - 1) / BATCH;
    __shared__ int v[512], s2[256];
    v[tid]       = (tid < nbatch)       ? hist_blk[tid * NB + b]         : 0;
    v[tid + 256] = (tid + 256 < nbatch) ? hist_blk[(tid + 256) * NB + b] : 0;
    __syncthreads();
    int pair = v[2 * tid] + v[2 * tid + 1];
    s2[tid] = pair;
    __syncthreads();
    for (int off = 1; off < 256; off <<= 1) {
        int t = (tid >= off) ? s2[tid - off] : 0;
        __syncthreads();
        s2[tid] += t;
        __syncthreads();
    }
    int e2 = s2[tid] - pair;
    if (2 * tid < nbatch)     bb[b * nbatch + 2 * tid]     = e2;
    if (2 * tid + 1 < nbatch) bb[b * nbatch + 2 * tid + 1] = e2 + v[2 * tid];
    if (tid == 255) bucket_tot[b] = s2[255];
}

// ---------------------------------------------------------------------------
// P2a (1 block): exclusive scan of bucket_tot -> bucket_base[257]
// ---------------------------------------------------------------------------
__global__ __launch_bounds__(256) void k_p2a(
    const int* __restrict__ bucket_tot, int* __restrict__ bucket_base)
{
    const int tid = threadIdx.x;
    __shared__ int a[NB];
    int tot = bucket_tot[tid];
    a[tid] = tot;
    __syncthreads();
    for (int off = 1; off < NB; off <<= 1) {
        int t = (tid >= off) ? a[tid - off] : 0;
        __syncthreads();
        a[tid] += t;
        __syncthreads();
    }
    bucket_base[tid] = a[tid] - tot;
    if (tid == NB - 1) bucket_base[NB] = a[tid];
}

// ---------------------------------------------------------------------------
// K4 = {P3 direct-scatter || fused conv+gemm}.
// P3 slimmed: per-(batch,bucket) output runs are contiguous (avg 64B =
// one line), so a direct scatter rec1[gbase[b]+atomicAdd(&cnt2[b],1)]
// gets line-level coalescing WITHOUT the LDS hist/scan/stage/re-read
// pipeline (was: 2 atomic passes, 8-iter scan, ~20 barriers -> now 1
// barrier, 1 atomic pass). Order within a run is an arbitrary
// permutation -- P4 re-ranks per node, so only ulp-level sum-order
// changes (same class as existing cnt2/cnt atomics).
// Kernel LDS drops 24.8 -> 17.9KB -> 8 blocks/CU (wave cap).
// Gemm branch: R13-exact.
// ---------------------------------------------------------------------------
__global__ __launch_bounds__(256) void k_p3convgemm(
    const int* __restrict__ src, const int* __restrict__ dst,
    const int* __restrict__ bb, const int* __restrict__ bucket_base,
    unsigned* __restrict__ rec1, int n_edges,
    const float* __restrict__ h,
    const unsigned short* __restrict__ w_hi, const unsigned short* __restrict__ w_lo,
    const float* __restrict__ attn_w,
    unsigned short* __restrict__ z_bf16, float* __restrict__ el, float* __restrict__ er,
    int n_nodes)
{
    __shared__ __align__(16) char smem[17920];
    const int tid = threadIdx.x;
    const int nbatch = (n_edges + BATCH - 1) / BATCH;

    if ((int)blockIdx.x < nbatch) {
        // ----- P3 direct scatter (2KB LDS) -----
        int* cnt2  = (int*)smem;          // NB
        int* gbase = cnt2 + NB;           // NB
        const int batch = blockIdx.x;
        const int e0 = batch * BATCH;
        const int n = min(BATCH, n_edges - e0);
        cnt2[tid] = 0;
        gbase[tid] = bucket_base[tid] + bb[tid * nbatch + batch];
        __syncthreads();
        #pragma unroll
        for (int k = 0; k < 16; ++k) {
            int j = tid + k * 256;
            if (j < n) {
                int d = dst[e0 + j];
                int s = src[e0 + j];
                int b = d >> 9;
                int r = atomicAdd(&cnt2[b], 1);
                rec1[gbase[b] + r] = ((unsigned)(d & 511) << 17) | (unsigned)s;
            }
        }
    } else {
        // ----- fused conv+gemm (R13-exact; 17.9 KB LDS) -----
        unsigned short* hstage = (unsigned short*)smem;        // 32*HROW bf16
        float* elp = (float*)(smem + 32 * HROW * 2);           // 4*32
        float* erp = elp + 128;                                // 4*32
        const int tile = blockIdx.x - nbatch;                  // exactly ntiles blocks
        const int lane = tid & 63;
        const int wave = tid >> 6;
        const int c    = lane & 15;
        const int g    = lane >> 4;
        const int c0   = wave * 16;

        const int n0 = tile << 5;
        float4 sv[8];
        #pragma unroll
        for (int rr = 0; rr < 8; ++rr) {
            int ridx = min(n0 + wave * 8 + rr, n_nodes - 1);
            sv[rr] = *(const float4*)(h + (size_t)ridx * 256 + lane * 4);
        }
        #pragma unroll
        for (int rr = 0; rr < 8; ++rr) {
            unsigned lo = cvtpk(sv[rr].x, sv[rr].y);
            unsigned hi = cvtpk(sv[rr].z, sv[rr].w);
            *(uint2*)&hstage[(wave * 8 + rr) * HROW + lane * 4] = make_uint2(lo, hi);
        }

        short8 bh[8], bl[8];
        #pragma unroll
        for (int t = 0; t < 8; ++t) {
            const int koff = (c0 + c) * 256 + t * 32 + g * 8;
            bh[t] = *(const short8*)(w_hi + koff);
            bl[t] = *(const short8*)(w_lo + koff);
        }
        const float wl_lane = attn_w[c0 + c];
        const float wr_lane = attn_w[64 + c0 + c];
        __syncthreads();

        f32x4 acc0 = {0.f, 0.f, 0.f, 0.f};
        f32x4 acc1 = {0.f, 0.f, 0.f, 0.f};
        #pragma unroll
        for (int t = 0; t < 8; ++t) {
            short8 a0 = *(const short8*)&hstage[c * HROW + t * 32 + g * 8];
            short8 a1 = *(const short8*)&hstage[(c + 16) * HROW + t * 32 + g * 8];
            acc0 = __builtin_amdgcn_mfma_f32_16x16x32_bf16(a0, bh[t], acc0, 0, 0, 0);
            acc1 = __builtin_amdgcn_mfma_f32_16x16x32_bf16(a1, bh[t], acc1, 0, 0, 0);
            acc0 = __builtin_amdgcn_mfma_f32_16x16x32_bf16(a0, bl[t], acc0, 0, 0, 0);
            acc1 = __builtin_amdgcn_mfma_f32_16x16x32_bf16(a1, bl[t], acc1, 0, 0, 0);
        }
        #pragma unroll
        for (int j = 0; j < 4; ++j) {
            int ra = n0 + 4 * g + j;
            int rb = ra + 16;
            if (ra < n_nodes) z_bf16[(size_t)ra * 64 + c0 + c] = f2bf_rne(acc0[j]);
            if (rb < n_nodes) z_bf16[(size_t)rb * 64 + c0 + c] = f2bf_rne(acc1[j]);
        }
        float pl0[4], pr0[4], pl1[4], pr1[4];
        #pragma unroll
        for (int j = 0; j < 4; ++j) {
            pl0[j] = acc0[j] * wl_lane; pr0[j] = acc0[j] * wr_lane;
            pl1[j] = acc1[j] * wl_lane; pr1[j] = acc1[j] * wr_lane;
        }
        #pragma unroll
        for (int off = 1; off < 16; off <<= 1) {
            #pragma unroll
            for (int j = 0; j < 4; ++j) {
                pl0[j] += __shfl_xor(pl0[j], off);
                pr0[j] += __shfl_xor(pr0[j], off);
                pl1[j] += __shfl_xor(pl1[j], off);
                pr1[j] += __shfl_xor(pr1[j], off);
            }
        }
        if (c == 0) {
            #pragma unroll
            for (int j = 0; j < 4; ++j) {
                elp[wave * 32 + 4 * g + j]      = pl0[j];
                elp[wave * 32 + 16 + 4 * g + j] = pl1[j];
                erp[wave * 32 + 4 * g + j]      = pr0[j];
                erp[wave * 32 + 16 + 4 * g + j] = pr1[j];
            }
        }
        __syncthreads();
        if (tid < 32) {
            if (n0 + tid < n_nodes)
                el[n0 + tid] = elp[tid] + elp[32 + tid] + elp[64 + tid] + elp[96 + tid];
        } else if (tid < 64) {
            int r = tid - 32;
            if (n0 + r < n_nodes)
                er[n0 + r] = erp[r] + erp[32 + r] + erp[64 + r] + erp[96 + r];
        }
    }
}

// ---------------------------------------------------------------------------
// P4 (NB blocks): 512-bin LDS count + scan -> rowstart; scatter
// (src, leaky(el+er)) int2 into final CSR order. LDS atomics only.
// ---------------------------------------------------------------------------
__global__ __launch_bounds__(256) void k_p4(
    const unsigned* __restrict__ rec1, const int* __restrict__ bucket_base,
    const float* __restrict__ el, const float* __restrict__ er,
    int* __restrict__ rowstart, int2* __restrict__ rec,
    int n_nodes, int n_edges)
{
    const int tid = threadIdx.x;
    const int b = blockIdx.x;
    const int beg  = bucket_base[b];
    const int endb = bucket_base[b + 1];
    const int nbuse = (n_nodes + 511) >> 9;
    __shared__ int cnt[512], offs[512], s2[256];
    cnt[tid] = 0; cnt[tid + 256] = 0;
    __syncthreads();
    for (int i = beg + tid; i < endb; i += 256)
        atomicAdd(&cnt[rec1[i] >> 17], 1);
    __syncthreads();
    int pair = cnt[2 * tid] + cnt[2 * tid + 1];
    s2[tid] = pair;
    __syncthreads();
    for (int off = 1; off < 256; off <<= 1) {
        int t = (tid >= off) ? s2[tid - off] : 0;
        __syncthreads();
        s2[tid] += t;
        __syncthreads();
    }
    int e2 = s2[tid] - pair;
    offs[2 * tid]     = e2;
    offs[2 * tid + 1] = e2 + cnt[2 * tid];
    __syncthreads();
    for (int t2 = tid; t2 < 512; t2 += 256) {
        int node = (b << 9) + t2;
        if (node < n_nodes) rowstart[node] = beg + offs[t2];
    }
    if (b == nbuse - 1 && tid == 0) rowstart[n_nodes] = n_edges;
    cnt[tid] = 0; cnt[tid + 256] = 0;
    __syncthreads();
    for (int i = beg + tid; i < endb; i += 256) {
        unsigned u = rec1[i];
        int rd = (int)(u >> 17);
        int s  = (int)(u & 0x1FFFFu);
        int r = atomicAdd(&cnt[rd], 1);
        float ev = el[s] + er[(b << 9) + rd];
        ev = (ev > 0.f) ? ev : NEG_SLOPE * ev;
        rec[beg + offs[rd] + r] = make_int2(s, __float_as_int(ev));
    }
}

// ---------------------------------------------------------------------------
// Aggregation (R13-exact): one wave per dst node, 4 edges via 16-lane
// groups, 8-edge clamped loop.
// ---------------------------------------------------------------------------
__global__ __launch_bounds__(256) void k_agg(
    const int* __restrict__ rowstart, const int2* __restrict__ rec,
    const unsigned short* __restrict__ z,
    const float* __restrict__ snorm, float* __restrict__ out, int n_nodes)
{
    const int wid  = (blockIdx.x * blockDim.x + threadIdx.x) >> 6;
    const int lane = threadIdx.x & 63;
    if (wid >= n_nodes) return;
    const int t = lane & 15;
    const int g = lane >> 4;
    const int start = rowstart[wid];
    const int end   = rowstart[wid + 1];
    if (end == start) {
        if (g == 0) *(float4*)(out + (size_t)wid * 64 + t * 4) = make_float4(0.f, 0.f, 0.f, 0.f);
        return;
    }
    float denom = 0.f;
    float acc0 = 0.f, acc1 = 0.f, acc2 = 0.f, acc3 = 0.f;
    const int last = end - 1;
    for (int ib = start; ib < end; ib += 8) {
        int iA = ib + g;
        int iB = ib + 4 + g;
        bool vA = iA < end, vB = iB < end;
        int2 eA = rec[min(iA, last)];
        int2 eB = rec[min(iB, last)];
        ushort4 za = *(const ushort4*)(z + (size_t)eA.x * 64 + t * 4);
        ushort4 zb = *(const ushort4*)(z + (size_t)eB.x * 64 + t * 4);
        float wA = vA ? __expf(__int_as_float(eA.y)) : 0.f;
        float wB = vB ? __expf(__int_as_float(eB.y)) : 0.f;
        denom += wA + wB;
        acc0 = fmaf(wA, bf2f(za.x), acc0);
        acc1 = fmaf(wA, bf2f(za.y), acc1);
        acc2 = fmaf(wA, bf2f(za.z), acc2);
        acc3 = fmaf(wA, bf2f(za.w), acc3);
        acc0 = fmaf(wB, bf2f(zb.x), acc0);
        acc1 = fmaf(wB, bf2f(zb.y), acc1);
        acc2 = fmaf(wB, bf2f(zb.z), acc2);
        acc3 = fmaf(wB, bf2f(zb.w), acc3);
    }
    #pragma unroll
    for (int off = 16; off <= 32; off <<= 1) {
        denom += __shfl_xor(denom, off);
        acc0  += __shfl_xor(acc0,  off);
        acc1  += __shfl_xor(acc1,  off);
        acc2  += __shfl_xor(acc2,  off);
        acc3  += __shfl_xor(acc3,  off);
    }
    if (g == 0) {
        float s = snorm[wid] / denom;
        float4 o;
        o.x = fmaxf(acc0 * s, 0.f);
        o.y = fmaxf(acc1 * s, 0.f);
        o.z = fmaxf(acc2 * s, 0.f);
        o.w = fmaxf(acc3 * s, 0.f);
        *(float4*)(out + (size_t)wid * 64 + t * 4) = o;
    }
}

// ---------------------------------------------------------------------------
extern "C" void kernel_launch(void* const* d_in, const int* in_sizes, int n_in,
                              void* d_out, int out_size, void* d_ws, size_t ws_size,
                              hipStream_t stream)
{
    const float* h      = (const float*)d_in[0];
    const float* snorm  = (const float*)d_in[1];
    const float* fc_w   = (const float*)d_in[2];
    const float* attn_w = (const float*)d_in[3];
    const int*   src    = (const int*)d_in[4];
    const int*   dst    = (const int*)d_in[5];
    float* out = (float*)d_out;

    const int n_nodes = in_sizes[1];
    const int n_edges = in_sizes[4];
    const int wdim    = in_sizes[2];   // 64*256
    const int nbatch  = (n_edges + BATCH - 1) / BATCH;
    const int nprep   = (wdim + 255) / 256;
    const int ntiles  = (n_nodes + 31) >> 5;

    char* wsp = (char*)d_ws;
    size_t off = 0;
    auto alloc = [&](size_t bytes) -> void* {
        void* p = wsp + off;
        off += (bytes + 255) & ~(size_t)255;
        return p;
    };
    unsigned short* z_bf16 = (unsigned short*)alloc((size_t)n_nodes * 64 * sizeof(unsigned short));
    unsigned short* w_hi   = (unsigned short*)alloc((size_t)wdim * sizeof(unsigned short));
    unsigned short* w_lo   = (unsigned short*)alloc((size_t)wdim * sizeof(unsigned short));
    float* el        = (float*)alloc((size_t)n_nodes * sizeof(float));
    float* er        = (float*)alloc((size_t)n_nodes * sizeof(float));
    int*   hist_blk  = (int*)  alloc((size_t)nbatch * NB * sizeof(int));
    int*   bucket_tot  = (int*)alloc((size_t)NB * sizeof(int));
    int*   bucket_base = (int*)alloc((size_t)(NB + 1) * sizeof(int));
    int*   bb        = (int*)  alloc((size_t)NB * nbatch * sizeof(int));
    int*   rowstart  = (int*)  alloc(((size_t)n_nodes + 1) * sizeof(int));
    unsigned* rec1   = (unsigned*)alloc((size_t)n_edges * sizeof(unsigned));
    int2*  rec       = (int2*) alloc((size_t)n_edges * sizeof(int2));

    k_hist<<<nbatch + nprep, 256, 0, stream>>>(
        dst, hist_blk, n_edges, fc_w, w_hi, w_lo, wdim);
    k_p2loc<<<NB, 256, 0, stream>>>(hist_blk, bb, bucket_tot, n_edges);
    k_p2a<<<1, 256, 0, stream>>>(bucket_tot, bucket_base);
    k_p3convgemm<<<nbatch + ntiles, 256, 0, stream>>>(
        src, dst, bb, bucket_base, rec1, n_edges,
        h, w_hi, w_lo, attn_w, z_bf16, el, er, n_nodes);
    k_p4<<<NB, 256, 0, stream>>>(rec1, bucket_base, el, er, rowstart, rec,
                                 n_nodes, n_edges);
    k_agg<<<((size_t)n_nodes * 64 + 255) / 256, 256, 0, stream>>>(
        rowstart, rec, z_bf16, snorm, out, n_nodes);
}

// Round 20
// 127.931 us; speedup vs baseline: 1.0454x; 1.0454x over previous
//
#include <hip/hip_runtime.h>
#include <math.h>

#define NEG_SLOPE 0.01f
#define NB 256           // buckets (bucket = dst >> 9, 512 nodes each)
#define BATCH 4096       // edges per hist/P3 batch (16 per thread)
#define HROW 264         // bf16 row stride in LDS: 256 elems + 8 pad (528 B)

typedef __attribute__((ext_vector_type(8))) short short8;
typedef __attribute__((ext_vector_type(4))) float f32x4;

__device__ __forceinline__ unsigned short f2bf_rne(float f) {
    unsigned u = __float_as_uint(f);
    unsigned r = 0x7fffu + ((u >> 16) & 1u);
    return (unsigned short)((u + r) >> 16);
}
__device__ __forceinline__ float bf2f(unsigned short b) {
    return __uint_as_float(((unsigned)b) << 16);
}
// 2 f32 -> 2 bf16 (RNE), single instruction (verified on-device R9/R11/R13)
__device__ __forceinline__ unsigned cvtpk(float lo, float hi) {
    unsigned r;
    asm("v_cvt_pk_bf16_f32 %0, %1, %2" : "=v"(r) : "v"(lo), "v"(hi));
    return r;
}

// ---------------------------------------------------------------------------
// K1 = {bucket-histogram || w-prep (fc_w -> bf16 hi/lo)} -- both cheap
// ---------------------------------------------------------------------------
__global__ __launch_bounds__(256) void k_hist(
    const int* __restrict__ dst, int* __restrict__ hist_blk, int n_edges,
    const float* __restrict__ fc_w,
    unsigned short* __restrict__ w_hi, unsigned short* __restrict__ w_lo, int wdim)
{
    const int tid = threadIdx.x;
    const int nbatch = (n_edges + BATCH - 1) / BATCH;
    if ((int)blockIdx.x < nbatch) {
        __shared__ int hist[NB];
        const int batch = blockIdx.x;
        hist[tid] = 0;
        __syncthreads();
        const int e0 = batch * BATCH;
        const int n = min(BATCH, n_edges - e0);
        #pragma unroll
        for (int k = 0; k < 16; ++k) {
            int j = tid + k * 256;
            if (j < n) atomicAdd(&hist[dst[e0 + j] >> 9], 1);
        }
        __syncthreads();
        hist_blk[batch * NB + tid] = hist[tid];
    } else {
        int i = (blockIdx.x - nbatch) * 256 + tid;
        if (i < wdim) {
            float f = fc_w[i];
            unsigned u = __float_as_uint(f);
            w_hi[i] = (unsigned short)(u >> 16);
            float lo = f - __uint_as_float(u & 0xffff0000u);
            w_lo[i] = f2bf_rne(lo);
        }
    }
}

// ---------------------------------------------------------------------------
// P2loc (NB blocks): per-bucket exclusive scan over batches -> bb (local),
// bucket_tot. Parallel across 256 CUs.
// ---------------------------------------------------------------------------
__global__ __launch_bounds__(256) void k_p2loc(
    const int* __restrict__ hist_blk, int* __restrict__ bb,
    int* __restrict__ bucket_tot, int n_edges)
{
    const int tid = threadIdx.x;
    const int b = blockIdx.x;
    const int nbatch = (n_edges + BATCH - 1) / BATCH;
    __shared__ int v[512], s2[256];
    v[tid]       = (tid < nbatch)       ? hist_blk[tid * NB + b]         : 0;
    v[tid + 256] = (tid + 256 < nbatch) ? hist_blk[(tid + 256) * NB + b] : 0;
    __syncthreads();
    int pair = v[2 * tid] + v[2 * tid + 1];
    s2[tid] = pair;
    __syncthreads();
    for (int off = 1; off < 256; off <<= 1) {
        int t = (tid >= off) ? s2[tid - off] : 0;
        __syncthreads();
        s2[tid] += t;
        __syncthreads();
    }
    int e2 = s2[tid] - pair;
    if (2 * tid < nbatch)     bb[b * nbatch + 2 * tid]     = e2;
    if (2 * tid + 1 < nbatch) bb[b * nbatch + 2 * tid + 1] = e2 + v[2 * tid];
    if (tid == 255) bucket_tot[b] = s2[255];
}

// ---------------------------------------------------------------------------
// P2a (1 block): exclusive scan of bucket_tot -> bucket_base[257]
// ---------------------------------------------------------------------------
__global__ __launch_bounds__(256) void k_p2a(
    const int* __restrict__ bucket_tot, int* __restrict__ bucket_base)
{
    const int tid = threadIdx.x;
    __shared__ int a[NB];
    int tot = bucket_tot[tid];
    a[tid] = tot;
    __syncthreads();
    for (int off = 1; off < NB; off <<= 1) {
        int t = (tid >= off) ? a[tid - off] : 0;
        __syncthreads();
        a[tid] += t;
        __syncthreads();
    }
    bucket_base[tid] = a[tid] - tot;
    if (tid == NB - 1) bucket_base[NB] = a[tid];
}

// ---------------------------------------------------------------------------
// K4 = {P3 bucket-scatter || fused conv+gemm}  (R13 exact form, 58us —
// empirical optimum of every axis probed: plain/high-occ/dbuf/async-ring/
// slim-P3 all >= it).
// convgemm: per 32-row tile, load f32 h (8 independent float4/lane),
// convert to bf16 DURING staging, stage into 17.9KB LDS (HROW=264);
// MFMA phase reads short8 directly. Kernel LDS = 24.6KB -> 6 blocks/CU.
// Gemm sub-grid = exactly ntiles (1 tile/block).
// ---------------------------------------------------------------------------
__global__ __launch_bounds__(256) void k_p3convgemm(
    const int* __restrict__ src, const int* __restrict__ dst,
    const int* __restrict__ bb, const int* __restrict__ bucket_base,
    unsigned* __restrict__ rec1, int n_edges,
    const float* __restrict__ h,
    const unsigned short* __restrict__ w_hi, const unsigned short* __restrict__ w_lo,
    const float* __restrict__ attn_w,
    unsigned short* __restrict__ z_bf16, float* __restrict__ el, float* __restrict__ er,
    int n_nodes)
{
    __shared__ __align__(16) char smem[24832];
    const int tid = threadIdx.x;
    const int nbatch = (n_edges + BATCH - 1) / BATCH;

    if ((int)blockIdx.x < nbatch) {
        // ----- P3 bucket scatter (aliased LDS: 24.6 KB) -----
        int* hist  = (int*)smem;                    // NB
        int* offs  = hist + NB;                     // NB
        int* cnt2  = offs + NB;                     // NB
        int* gbase = cnt2 + NB;                     // NB
        unsigned* staged = (unsigned*)(gbase + NB); // BATCH
        unsigned char* sbkt = (unsigned char*)(staged + BATCH); // BATCH
        const int batch = blockIdx.x;
        const int e0 = batch * BATCH;
        const int n = min(BATCH, n_edges - e0);
        hist[tid] = 0; cnt2[tid] = 0;
        gbase[tid] = bucket_base[tid] + bb[tid * nbatch + batch];
        __syncthreads();
        int d[16], s[16];
        #pragma unroll
        for (int k = 0; k < 16; ++k) {
            int j = tid + k * 256;
            if (j < n) {
                d[k] = dst[e0 + j];
                s[k] = src[e0 + j];
                atomicAdd(&hist[d[k] >> 9], 1);
            } else d[k] = -1;
        }
        __syncthreads();
        int hv = hist[tid];
        for (int off = 1; off < NB; off <<= 1) {
            int t = (tid >= off) ? hist[tid - off] : 0;
            __syncthreads();
            hist[tid] += t;
            __syncthreads();
        }
        offs[tid] = hist[tid] - hv;
        __syncthreads();
        #pragma unroll
        for (int k = 0; k < 16; ++k) {
            if (d[k] >= 0) {
                int b = d[k] >> 9;
                int r = atomicAdd(&cnt2[b], 1);
                int slot = offs[b] + r;
                staged[slot] = ((unsigned)(d[k] & 511) << 17) | (unsigned)s[k];
                sbkt[slot] = (unsigned char)b;
            }
        }
        __syncthreads();
        #pragma unroll
        for (int k = 0; k < 16; ++k) {
            int j = tid + k * 256;
            if (j < n) {
                int b = sbkt[j];
                rec1[gbase[b] + (j - offs[b])] = staged[j];
            }
        }
    } else {
        // ----- fused conv+gemm (aliased LDS: 17.9 KB of the 24.6) -----
        unsigned short* hstage = (unsigned short*)smem;        // 32*HROW bf16
        float* elp = (float*)(smem + 32 * HROW * 2);           // 4*32
        float* erp = elp + 128;                                // 4*32
        const int tile = blockIdx.x - nbatch;                  // exactly ntiles blocks
        const int lane = tid & 63;
        const int wave = tid >> 6;
        const int c    = lane & 15;
        const int g    = lane >> 4;
        const int c0   = wave * 16;

        const int n0 = tile << 5;
        float4 sv[8];
        #pragma unroll
        for (int rr = 0; rr < 8; ++rr) {
            int ridx = min(n0 + wave * 8 + rr, n_nodes - 1);
            sv[rr] = *(const float4*)(h + (size_t)ridx * 256 + lane * 4);
        }
        #pragma unroll
        for (int rr = 0; rr < 8; ++rr) {
            unsigned lo = cvtpk(sv[rr].x, sv[rr].y);
            unsigned hi = cvtpk(sv[rr].z, sv[rr].w);
            *(uint2*)&hstage[(wave * 8 + rr) * HROW + lane * 4] = make_uint2(lo, hi);
        }

        short8 bh[8], bl[8];
        #pragma unroll
        for (int t = 0; t < 8; ++t) {
            const int koff = (c0 + c) * 256 + t * 32 + g * 8;
            bh[t] = *(const short8*)(w_hi + koff);
            bl[t] = *(const short8*)(w_lo + koff);
        }
        const float wl_lane = attn_w[c0 + c];
        const float wr_lane = attn_w[64 + c0 + c];
        __syncthreads();

        f32x4 acc0 = {0.f, 0.f, 0.f, 0.f};
        f32x4 acc1 = {0.f, 0.f, 0.f, 0.f};
        #pragma unroll
        for (int t = 0; t < 8; ++t) {
            short8 a0 = *(const short8*)&hstage[c * HROW + t * 32 + g * 8];
            short8 a1 = *(const short8*)&hstage[(c + 16) * HROW + t * 32 + g * 8];
            acc0 = __builtin_amdgcn_mfma_f32_16x16x32_bf16(a0, bh[t], acc0, 0, 0, 0);
            acc1 = __builtin_amdgcn_mfma_f32_16x16x32_bf16(a1, bh[t], acc1, 0, 0, 0);
            acc0 = __builtin_amdgcn_mfma_f32_16x16x32_bf16(a0, bl[t], acc0, 0, 0, 0);
            acc1 = __builtin_amdgcn_mfma_f32_16x16x32_bf16(a1, bl[t], acc1, 0, 0, 0);
        }
        #pragma unroll
        for (int j = 0; j < 4; ++j) {
            int ra = n0 + 4 * g + j;
            int rb = ra + 16;
            if (ra < n_nodes) z_bf16[(size_t)ra * 64 + c0 + c] = f2bf_rne(acc0[j]);
            if (rb < n_nodes) z_bf16[(size_t)rb * 64 + c0 + c] = f2bf_rne(acc1[j]);
        }
        float pl0[4], pr0[4], pl1[4], pr1[4];
        #pragma unroll
        for (int j = 0; j < 4; ++j) {
            pl0[j] = acc0[j] * wl_lane; pr0[j] = acc0[j] * wr_lane;
            pl1[j] = acc1[j] * wl_lane; pr1[j] = acc1[j] * wr_lane;
        }
        #pragma unroll
        for (int off = 1; off < 16; off <<= 1) {
            #pragma unroll
            for (int j = 0; j < 4; ++j) {
                pl0[j] += __shfl_xor(pl0[j], off);
                pr0[j] += __shfl_xor(pr0[j], off);
                pl1[j] += __shfl_xor(pl1[j], off);
                pr1[j] += __shfl_xor(pr1[j], off);
            }
        }
        if (c == 0) {
            #pragma unroll
            for (int j = 0; j < 4; ++j) {
                elp[wave * 32 + 4 * g + j]      = pl0[j];
                elp[wave * 32 + 16 + 4 * g + j] = pl1[j];
                erp[wave * 32 + 4 * g + j]      = pr0[j];
                erp[wave * 32 + 16 + 4 * g + j] = pr1[j];
            }
        }
        __syncthreads();
        if (tid < 32) {
            if (n0 + tid < n_nodes)
                el[n0 + tid] = elp[tid] + elp[32 + tid] + elp[64 + tid] + elp[96 + tid];
        } else if (tid < 64) {
            int r = tid - 32;
            if (n0 + r < n_nodes)
                er[n0 + r] = erp[r] + erp[32 + r] + erp[64 + r] + erp[96 + r];
        }
    }
}

// ---------------------------------------------------------------------------
// P4 (NB blocks): 512-bin LDS count + scan -> rowstart; scatter
// (src, leaky(el+er)) int2 into final CSR order. LDS atomics only.
// ---------------------------------------------------------------------------
__global__ __launch_bounds__(256) void k_p4(
    const unsigned* __restrict__ rec1, const int* __restrict__ bucket_base,
    const float* __restrict__ el, const float* __restrict__ er,
    int* __restrict__ rowstart, int2* __restrict__ rec,
    int n_nodes, int n_edges)
{
    const int tid = threadIdx.x;
    const int b = blockIdx.x;
    const int beg  = bucket_base[b];
    const int endb = bucket_base[b + 1];
    const int nbuse = (n_nodes + 511) >> 9;
    __shared__ int cnt[512], offs[512], s2[256];
    cnt[tid] = 0; cnt[tid + 256] = 0;
    __syncthreads();
    for (int i = beg + tid; i < endb; i += 256)
        atomicAdd(&cnt[rec1[i] >> 17], 1);
    __syncthreads();
    int pair = cnt[2 * tid] + cnt[2 * tid + 1];
    s2[tid] = pair;
    __syncthreads();
    for (int off = 1; off < 256; off <<= 1) {
        int t = (tid >= off) ? s2[tid - off] : 0;
        __syncthreads();
        s2[tid] += t;
        __syncthreads();
    }
    int e2 = s2[tid] - pair;
    offs[2 * tid]     = e2;
    offs[2 * tid + 1] = e2 + cnt[2 * tid];
    __syncthreads();
    for (int t2 = tid; t2 < 512; t2 += 256) {
        int node = (b << 9) + t2;
        if (node < n_nodes) rowstart[node] = beg + offs[t2];
    }
    if (b == nbuse - 1 && tid == 0) rowstart[n_nodes] = n_edges;
    cnt[tid] = 0; cnt[tid + 256] = 0;
    __syncthreads();
    for (int i = beg + tid; i < endb; i += 256) {
        unsigned u = rec1[i];
        int rd = (int)(u >> 17);
        int s  = (int)(u & 0x1FFFFu);
        int r = atomicAdd(&cnt[rd], 1);
        float ev = el[s] + er[(b << 9) + rd];
        ev = (ev > 0.f) ? ev : NEG_SLOPE * ev;
        rec[beg + offs[rd] + r] = make_int2(s, __float_as_int(ev));
    }
}

// ---------------------------------------------------------------------------
// Aggregation (R13-exact): one wave per dst node, 4 edges via 16-lane
// groups, 8-edge clamped loop.
// ---------------------------------------------------------------------------
__global__ __launch_bounds__(256) void k_agg(
    const int* __restrict__ rowstart, const int2* __restrict__ rec,
    const unsigned short* __restrict__ z,
    const float* __restrict__ snorm, float* __restrict__ out, int n_nodes)
{
    const int wid  = (blockIdx.x * blockDim.x + threadIdx.x) >> 6;
    const int lane = threadIdx.x & 63;
    if (wid >= n_nodes) return;
    const int t = lane & 15;
    const int g = lane >> 4;
    const int start = rowstart[wid];
    const int end   = rowstart[wid + 1];
    if (end == start) {
        if (g == 0) *(float4*)(out + (size_t)wid * 64 + t * 4) = make_float4(0.f, 0.f, 0.f, 0.f);
        return;
    }
    float denom = 0.f;
    float acc0 = 0.f, acc1 = 0.f, acc2 = 0.f, acc3 = 0.f;
    const int last = end - 1;
    for (int ib = start; ib < end; ib += 8) {
        int iA = ib + g;
        int iB = ib + 4 + g;
        bool vA = iA < end, vB = iB < end;
        int2 eA = rec[min(iA, last)];
        int2 eB = rec[min(iB, last)];
        ushort4 za = *(const ushort4*)(z + (size_t)eA.x * 64 + t * 4);
        ushort4 zb = *(const ushort4*)(z + (size_t)eB.x * 64 + t * 4);
        float wA = vA ? __expf(__int_as_float(eA.y)) : 0.f;
        float wB = vB ? __expf(__int_as_float(eB.y)) : 0.f;
        denom += wA + wB;
        acc0 = fmaf(wA, bf2f(za.x), acc0);
        acc1 = fmaf(wA, bf2f(za.y), acc1);
        acc2 = fmaf(wA, bf2f(za.z), acc2);
        acc3 = fmaf(wA, bf2f(za.w), acc3);
        acc0 = fmaf(wB, bf2f(zb.x), acc0);
        acc1 = fmaf(wB, bf2f(zb.y), acc1);
        acc2 = fmaf(wB, bf2f(zb.z), acc2);
        acc3 = fmaf(wB, bf2f(zb.w), acc3);
    }
    #pragma unroll
    for (int off = 16; off <= 32; off <<= 1) {
        denom += __shfl_xor(denom, off);
        acc0  += __shfl_xor(acc0,  off);
        acc1  += __shfl_xor(acc1,  off);
        acc2  += __shfl_xor(acc2,  off);
        acc3  += __shfl_xor(acc3,  off);
    }
    if (g == 0) {
        float s = snorm[wid] / denom;
        float4 o;
        o.x = fmaxf(acc0 * s, 0.f);
        o.y = fmaxf(acc1 * s, 0.f);
        o.z = fmaxf(acc2 * s, 0.f);
        o.w = fmaxf(acc3 * s, 0.f);
        *(float4*)(out + (size_t)wid * 64 + t * 4) = o;
    }
}

// ---------------------------------------------------------------------------
extern "C" void kernel_launch(void* const* d_in, const int* in_sizes, int n_in,
                              void* d_out, int out_size, void* d_ws, size_t ws_size,
                              hipStream_t stream)
{
    const float* h      = (const float*)d_in[0];
    const float* snorm  = (const float*)d_in[1];
    const float* fc_w   = (const float*)d_in[2];
    const float* attn_w = (const float*)d_in[3];
    const int*   src    = (const int*)d_in[4];
    const int*   dst    = (const int*)d_in[5];
    float* out = (float*)d_out;

    const int n_nodes = in_sizes[1];
    const int n_edges = in_sizes[4];
    const int wdim    = in_sizes[2];   // 64*256
    const int nbatch  = (n_edges + BATCH - 1) / BATCH;
    const int nprep   = (wdim + 255) / 256;
    const int ntiles  = (n_nodes + 31) >> 5;

    char* wsp = (char*)d_ws;
    size_t off = 0;
    auto alloc = [&](size_t bytes) -> void* {
        void* p = wsp + off;
        off += (bytes + 255) & ~(size_t)255;
        return p;
    };
    unsigned short* z_bf16 = (unsigned short*)alloc((size_t)n_nodes * 64 * sizeof(unsigned short));
    unsigned short* w_hi   = (unsigned short*)alloc((size_t)wdim * sizeof(unsigned short));
    unsigned short* w_lo   = (unsigned short*)alloc((size_t)wdim * sizeof(unsigned short));
    float* el        = (float*)alloc((size_t)n_nodes * sizeof(float));
    float* er        = (float*)alloc((size_t)n_nodes * sizeof(float));
    int*   hist_blk  = (int*)  alloc((size_t)nbatch * NB * sizeof(int));
    int*   bucket_tot  = (int*)alloc((size_t)NB * sizeof(int));
    int*   bucket_base = (int*)alloc((size_t)(NB + 1) * sizeof(int));
    int*   bb        = (int*)  alloc((size_t)NB * nbatch * sizeof(int));
    int*   rowstart  = (int*)  alloc(((size_t)n_nodes + 1) * sizeof(int));
    unsigned* rec1   = (unsigned*)alloc((size_t)n_edges * sizeof(unsigned));
    int2*  rec       = (int2*) alloc((size_t)n_edges * sizeof(int2));

    k_hist<<<nbatch + nprep, 256, 0, stream>>>(
        dst, hist_blk, n_edges, fc_w, w_hi, w_lo, wdim);
    k_p2loc<<<NB, 256, 0, stream>>>(hist_blk, bb, bucket_tot, n_edges);
    k_p2a<<<1, 256, 0, stream>>>(bucket_tot, bucket_base);
    k_p3convgemm<<<nbatch + ntiles, 256, 0, stream>>>(
        src, dst, bb, bucket_base, rec1, n_edges,
        h, w_hi, w_lo, attn_w, z_bf16, el, er, n_nodes);
    k_p4<<<NB, 256, 0, stream>>>(rec1, bucket_base, el, er, rowstart, rec,
                                 n_nodes, n_edges);
    k_agg<<<((size_t)n_nodes * 64 + 255) / 256, 256, 0, stream>>>(
        rowstart, rec, z_bf16, snorm, out, n_nodes);
}